// Round 4
// baseline (494.327 us; speedup 1.0000x reference)
//
#include <hip/hip_runtime.h>

typedef unsigned short u16;
typedef unsigned int u32;

#define SEQ 96
#define DM 512
#define NBATCH 512
#define NFREQ 49
#define CUT 16
#define MROWS (NBATCH * SEQ)  // 49152

typedef __attribute__((ext_vector_type(8))) short bf16x8;
typedef __attribute__((ext_vector_type(4))) float f32x4;

// ---------- bf16 helpers (manual, RNE) ----------
__device__ __forceinline__ u16 f2bf(float f) {
  u32 u = __float_as_uint(f);
  u32 r = (u + 0x7fffu + ((u >> 16) & 1u)) >> 16;
  return (u16)r;
}
__device__ __forceinline__ float bf2f(u16 u) {
  return __uint_as_float(((u32)u) << 16);
}

// async global->LDS, 16B per lane; lds base wave-uniform, lands at base+lane*16.
__device__ __forceinline__ void g2l16(const void* g, void* l) {
  __builtin_amdgcn_global_load_lds(
      (const __attribute__((address_space(1))) void*)g,
      (__attribute__((address_space(3))) void*)l, 16, 0, 0);
}

// ---------- K1: build spectral filter matrices Fl/Fh [96x96] bf16 ----------
__global__ void build_filters_k(const float* __restrict__ w,
                                u16* __restrict__ FlB, u16* __restrict__ FhB) {
  int idx = blockIdx.x * 256 + threadIdx.x;
  if (idx >= SEQ * SEQ) return;
  int s = idx / SEQ, t = idx % SEQ;
  int d = s - t;
  const float scale = 1.0f / (float)SEQ;
  const float w0 = 6.283185307179586f / (float)SEQ;
  float cl = 0.f, ch = 0.f;
  for (int k = 0; k < NFREQ; k++) {
    int m = (k * d) % SEQ;
    if (m < 0) m += SEQ;
    float c = (k == 0 || k == SEQ / 2) ? 1.0f : 2.0f;
    float v = c * w[k] * cosf(w0 * (float)m) * scale;
    if (k < CUT) cl += v; else ch += v;
  }
  FlB[idx] = f2bf(cl);
  FhB[idx] = f2bf(ch);
}

// ---------- K1b: transpose fp32 [K,N] weight -> bf16 [N,K] ----------
__global__ void __launch_bounds__(256) transpose_w_k(
    const float* __restrict__ W, u16* __restrict__ Wt, int K, int N) {
  __shared__ float t[32][33];
  int k0 = blockIdx.x * 32, n0 = blockIdx.y * 32;
  int tx = threadIdx.x & 31, ty = threadIdx.x >> 5;  // ty 0..7
  #pragma unroll
  for (int r = 0; r < 32; r += 8)
    t[ty + r][tx] = W[(size_t)(k0 + ty + r) * N + n0 + tx];
  __syncthreads();
  #pragma unroll
  for (int r = 0; r < 32; r += 8)
    Wt[(size_t)(n0 + ty + r) * K + k0 + tx] = f2bf(t[tx][ty + r]);
}

// ---------- K2: xb = bf16(x), flat [MROWS*512] ----------
__global__ void __launch_bounds__(256) xb_k(const float* __restrict__ x,
                                            u16* __restrict__ xb) {
  size_t t = ((size_t)blockIdx.x * 256 + threadIdx.x) * 8;
  float4 f0 = *(const float4*)(x + t);
  float4 f1 = *(const float4*)(x + t + 4);
  uint4 o;
  o.x = (u32)f2bf(f0.x) | ((u32)f2bf(f0.y) << 16);
  o.y = (u32)f2bf(f0.z) | ((u32)f2bf(f0.w) << 16);
  o.z = (u32)f2bf(f1.x) | ((u32)f2bf(f1.y) << 16);
  o.w = (u32)f2bf(f1.z) | ((u32)f2bf(f1.w) << 16);
  *(uint4*)(xb + t) = o;
}

// ---------- K3: dual proj GEMM: [u|v] = xb @ [Wl|Wh], epilogue writes
// uT/vT in [b][e][s] bf16 layout (transposed, ready for filter stage).
// Wt = stacked [Wl^T ; Wh^T] : [1024][512]. NO bias here (bias after filter).
__global__ void __launch_bounds__(256) proj_dual_k(
    const u16* __restrict__ xb, const u16* __restrict__ Wt,
    u16* __restrict__ uT, u16* __restrict__ vT) {
  __shared__ __align__(16) u16 As[128 * 64];
  __shared__ __align__(16) u16 Bs[128 * 64];
  const int m0 = blockIdx.x * 128;
  const int n0 = blockIdx.y * 128;  // over 1024 virtual N
  const int tid = threadIdx.x;
  const int lane = tid & 63;
  const int w = tid >> 6;
  const int wm = w & 1, wn = w >> 1;
  const int l15 = lane & 15;
  const int lq = lane >> 4;

  f32x4 acc[4][4] = {};

  for (int kt = 0; kt < 512; kt += 64) {
    #pragma unroll
    for (int r = 0; r < 4; r++) {
      int c = r * 256 + tid;          // 0..1023 16B chunks
      int row = c >> 3;               // 0..127
      int off = (c & 7) << 3;         // elem offset in 64-elem row
      u32 lo = (u32)((r * 256 + w * 64) << 4);
      g2l16(xb + (size_t)(m0 + row) * 512 + kt + off, (char*)As + lo);
      g2l16(Wt + (size_t)(n0 + row) * 512 + kt + off, (char*)Bs + lo);
    }
    __syncthreads();
    #pragma unroll
    for (int kk = 0; kk < 64; kk += 32) {
      bf16x8 af[4], bf[4];
      #pragma unroll
      for (int i = 0; i < 4; i++)
        af[i] = *(const bf16x8*)&As[(wm * 64 + i * 16 + l15) * 64 + kk + lq * 8];
      #pragma unroll
      for (int j = 0; j < 4; j++)
        bf[j] = *(const bf16x8*)&Bs[(wn * 64 + j * 16 + l15) * 64 + kk + lq * 8];
      #pragma unroll
      for (int i = 0; i < 4; i++)
        #pragma unroll
        for (int j = 0; j < 4; j++)
          acc[i][j] = __builtin_amdgcn_mfma_f32_16x16x32_bf16(af[i], bf[j], acc[i][j], 0, 0, 0);
    }
    __syncthreads();
  }

  // epilogue: m = b*96+s ; write dst[b][e][s] ; 4 consecutive s per lane.
  #pragma unroll
  for (int j = 0; j < 4; j++) {
    int nv = n0 + wn * 64 + j * 16 + l15;
    u16* dst = (nv < 512) ? uT : vT;
    int e = nv & 511;
    #pragma unroll
    for (int i = 0; i < 4; i++) {
      int mbase = m0 + wm * 64 + i * 16 + lq * 4;
      int b = mbase / 96, s = mbase % 96;  // s%4==0 -> never crosses batch
      ushort4 st;
      st.x = f2bf(acc[i][j][0]);
      st.y = f2bf(acc[i][j][1]);
      st.z = f2bf(acc[i][j][2]);
      st.w = f2bf(acc[i][j][3]);
      *(ushort4*)&dst[((size_t)b * 512 + e) * SEQ + s] = st;
    }
  }
}

// ---------- K4: yl = Fl@u + bl, yh = Fh@v + bh (per batch, via MFMA) ----------
// grid (NBATCH, DM/64). 4 waves: w&1 -> d-half (32), w>>1 -> {l,h}.
__global__ void __launch_bounds__(256) filter2_k(
    const u16* __restrict__ uT, const u16* __restrict__ vT,
    const u16* __restrict__ FlB, const u16* __restrict__ FhB,
    const float* __restrict__ bl, const float* __restrict__ bh,
    u16* __restrict__ yl, u16* __restrict__ yh) {
  __shared__ __align__(16) u16 lds[2 * SEQ * SEQ + 2 * 64 * SEQ];  // 61440 B
  u16* Fls = lds;                  // [96][96]
  u16* Bu = lds + 2 * SEQ * SEQ;   // [64 d][96 t]
  u16* Bv = Bu + 64 * SEQ;
  const int tid = threadIdx.x;
  const int lane = tid & 63, w = tid >> 6;
  const int b = blockIdx.x, d0 = blockIdx.y * 64;

  // stage Fl then Fh contiguous: 2*1152 chunks
  #pragma unroll
  for (int it = 0; it < 9; it++) {
    int c = it * 256 + tid;
    const u16* src = (c < 1152) ? (FlB + c * 8) : (FhB + (c - 1152) * 8);
    g2l16(src, (char*)Fls + ((it * 256 + w * 64) << 4));
  }
  // stage Bu/Bv: 64 rows x 192B = 768 chunks each
  const u16* bu = uT + ((size_t)b * 512 + d0) * SEQ;
  const u16* bv = vT + ((size_t)b * 512 + d0) * SEQ;
  #pragma unroll
  for (int it = 0; it < 3; it++) {
    int c = it * 256 + tid;
    int row = c / 12, off = (c % 12) * 8;
    u32 lo = (u32)((it * 256 + w * 64) << 4);
    g2l16(bu + (size_t)row * SEQ + off, (char*)Bu + lo);
    g2l16(bv + (size_t)row * SEQ + off, (char*)Bv + lo);
  }
  __syncthreads();

  const int wf = w >> 1, wd = w & 1;
  const int l15 = lane & 15, lq = lane >> 4;
  const u16* F = wf ? (Fls + SEQ * SEQ) : Fls;
  const u16* Bsrc = wf ? Bv : Bu;
  f32x4 acc[6][2] = {};
  #pragma unroll
  for (int ks = 0; ks < 3; ks++) {
    int kt = ks * 32;
    bf16x8 bf[2];
    #pragma unroll
    for (int j = 0; j < 2; j++)
      bf[j] = *(const bf16x8*)&Bsrc[(wd * 32 + j * 16 + l15) * SEQ + kt + lq * 8];
    #pragma unroll
    for (int i = 0; i < 6; i++) {
      bf16x8 af = *(const bf16x8*)&F[(i * 16 + l15) * SEQ + kt + lq * 8];
      #pragma unroll
      for (int j = 0; j < 2; j++)
        acc[i][j] = __builtin_amdgcn_mfma_f32_16x16x32_bf16(af, bf[j], acc[i][j], 0, 0, 0);
    }
  }
  const float* bias = wf ? bh : bl;
  u16* dst = wf ? yh : yl;
  #pragma unroll
  for (int j = 0; j < 2; j++) {
    int d = d0 + wd * 32 + j * 16 + l15;
    float bv2 = bias[d];
    #pragma unroll
    for (int i = 0; i < 6; i++)
      #pragma unroll
      for (int r = 0; r < 4; r++) {
        int s = i * 16 + lq * 4 + r;
        dst[((size_t)b * SEQ + s) * DM + d] = f2bf(acc[i][j][r] + bv2);
      }
  }
}

// ---------- K5: gate (K=1024 over concat(yl,yh)), BK=64, sigmoid epilogue ----------
__global__ void __launch_bounds__(256) gemm_gate_mfma_k(
    const u16* __restrict__ yl, const u16* __restrict__ yh,
    const u16* __restrict__ Wgt, const float* __restrict__ bg,
    u16* __restrict__ g) {
  __shared__ __align__(16) u16 As[128 * 64];
  __shared__ __align__(16) u16 Bs[128 * 64];
  const int m0 = blockIdx.x * 128;
  const int n0 = blockIdx.y * 128;
  const int tid = threadIdx.x;
  const int lane = tid & 63;
  const int w = tid >> 6;
  const int wm = w & 1, wn = w >> 1;
  const int l15 = lane & 15;
  const int lq = lane >> 4;

  f32x4 acc[4][4] = {};

  for (int kt = 0; kt < 1024; kt += 64) {
    const u16* Ak = (kt < 512) ? yl : yh;
    int ka = kt & 511;
    #pragma unroll
    for (int r = 0; r < 4; r++) {
      int c = r * 256 + tid;
      int row = c >> 3;
      int off = (c & 7) << 3;
      u32 lo = (u32)((r * 256 + w * 64) << 4);
      g2l16(Ak + (size_t)(m0 + row) * 512 + ka + off, (char*)As + lo);
      g2l16(Wgt + (size_t)(n0 + row) * 1024 + kt + off, (char*)Bs + lo);
    }
    __syncthreads();
    #pragma unroll
    for (int kk = 0; kk < 64; kk += 32) {
      bf16x8 af[4], bf[4];
      #pragma unroll
      for (int i = 0; i < 4; i++)
        af[i] = *(const bf16x8*)&As[(wm * 64 + i * 16 + l15) * 64 + kk + lq * 8];
      #pragma unroll
      for (int j = 0; j < 4; j++)
        bf[j] = *(const bf16x8*)&Bs[(wn * 64 + j * 16 + l15) * 64 + kk + lq * 8];
      #pragma unroll
      for (int i = 0; i < 4; i++)
        #pragma unroll
        for (int j = 0; j < 4; j++)
          acc[i][j] = __builtin_amdgcn_mfma_f32_16x16x32_bf16(af[i], bf[j], acc[i][j], 0, 0, 0);
    }
    __syncthreads();
  }

  #pragma unroll
  for (int j = 0; j < 4; j++) {
    int n = n0 + wn * 64 + j * 16 + l15;
    float bv = bg[n];
    #pragma unroll
    for (int i = 0; i < 4; i++) {
      int mrow = m0 + wm * 64 + i * 16 + lq * 4;
      #pragma unroll
      for (int r = 0; r < 4; r++) {
        float z = acc[i][j][r] + bv;
        g[(size_t)(mrow + r) * 512 + n] = f2bf(1.0f / (1.0f + __expf(-z)));
      }
    }
  }
}

// ---------- K6: y = x + g*yl + (1-g)*yh ; LayerNorm(y)*gamma + beta ----------
__global__ void __launch_bounds__(256) final_ln_k(
    const float* __restrict__ x, const u16* __restrict__ yl,
    const u16* __restrict__ yh, const u16* __restrict__ g,
    const float* __restrict__ gamma, const float* __restrict__ beta,
    float* __restrict__ out) {
  __shared__ float red[8];
  int r = blockIdx.x;
  size_t base = (size_t)r * 512;
  float vv[2];
  float sum = 0.f, sumsq = 0.f;
  #pragma unroll
  for (int j = 0; j < 2; j++) {
    int e = threadIdx.x + j * 256;
    float lv = bf2f(yl[base + e]);
    float hv = bf2f(yh[base + e]);
    float gv = bf2f(g[base + e]);
    float v = x[base + e] + gv * lv + (1.f - gv) * hv;
    vv[j] = v;
    sum += v;
    sumsq += v * v;
  }
  #pragma unroll
  for (int off = 32; off; off >>= 1) {
    sum += __shfl_down(sum, off);
    sumsq += __shfl_down(sumsq, off);
  }
  int wid = threadIdx.x >> 6;
  if ((threadIdx.x & 63) == 0) {
    red[wid] = sum;
    red[4 + wid] = sumsq;
  }
  __syncthreads();
  sum = red[0] + red[1] + red[2] + red[3];
  sumsq = red[4] + red[5] + red[6] + red[7];
  float mu = sum * (1.f / 512.f);
  float var = sumsq * (1.f / 512.f) - mu * mu;
  float inv = rsqrtf(var + 1e-5f);
  #pragma unroll
  for (int j = 0; j < 2; j++) {
    int e = threadIdx.x + j * 256;
    out[base + e] = (vv[j] - mu) * inv * gamma[e] + beta[e];
  }
}

extern "C" void kernel_launch(void* const* d_in, const int* in_sizes, int n_in,
                              void* d_out, int out_size, void* d_ws, size_t ws_size,
                              hipStream_t stream) {
  const float* x     = (const float*)d_in[0];
  const float* fw    = (const float*)d_in[1];
  const float* Wl    = (const float*)d_in[2];
  const float* bl    = (const float*)d_in[3];
  const float* Wh    = (const float*)d_in[4];
  const float* bh    = (const float*)d_in[5];
  const float* Wg    = (const float*)d_in[6];
  const float* bg    = (const float*)d_in[7];
  const float* gamma = (const float*)d_in[8];
  const float* beta  = (const float*)d_in[9];
  float* out = (float*)d_out;

  char* ws = (char*)d_ws;
  u16* FlB = (u16*)ws;                        // 96*96 bf16
  u16* FhB = FlB + SEQ * SEQ;
  u16* Wt  = (u16*)(ws + 64 * 1024);          // [1024][512] stacked Wl^T,Wh^T
  u16* Wgt = Wt + 1024 * 512;                 // [512][1024]
  size_t tsz = (size_t)MROWS * 512;           // 25165824 elems (50.3 MB bf16)
  u16* xb = (u16*)(ws + 4 * 1024 * 1024);     // xb, later reused as yl
  u16* uT = xb + tsz;                         // uT, later reused as g
  u16* vT = uT + tsz;
  u16* yh = vT + tsz;
  u16* yl = xb;    // filter2 writes yl after proj consumed xb
  u16* gb = uT;    // gate writes g after filter2 consumed uT

  build_filters_k<<<dim3(36), dim3(256), 0, stream>>>(fw, FlB, FhB);
  transpose_w_k<<<dim3(16, 16), dim3(256), 0, stream>>>(Wl, Wt, 512, 512);
  transpose_w_k<<<dim3(16, 16), dim3(256), 0, stream>>>(Wh, Wt + 512 * 512, 512, 512);
  transpose_w_k<<<dim3(32, 16), dim3(256), 0, stream>>>(Wg, Wgt, 1024, 512);
  xb_k<<<dim3(MROWS * 512 / 2048), dim3(256), 0, stream>>>(x, xb);
  proj_dual_k<<<dim3(MROWS / 128, 8), dim3(256), 0, stream>>>(xb, Wt, uT, vT);
  filter2_k<<<dim3(NBATCH, DM / 64), dim3(256), 0, stream>>>(
      uT, vT, FlB, FhB, bl, bh, yl, yh);
  gemm_gate_mfma_k<<<dim3(MROWS / 128, 4), dim3(256), 0, stream>>>(yl, yh, Wgt, bg, gb);
  final_ln_k<<<dim3(MROWS), dim3(256), 0, stream>>>(x, yl, yh, gb, gamma, beta, out);
}